// Round 14
// baseline (366.247 us; speedup 1.0000x reference)
//
#include <hip/hip_runtime.h>
#include <hip/hip_bf16.h>
#include <math.h>

// Problem dims (fixed)
#define BT    4096     // B*T rows
#define TSEQ  2048
#define DMODEL 1024
#define EDIM  2048
#define E2    4096     // 2*E
#define GG    16       // groups
#define NS    16       // state
#define DFF   4096
#define NCH   64       // scan chunks
#define CL    32       // chunk length (NCH*CL == TSEQ)

typedef __attribute__((ext_vector_type(8))) short short8_t;
typedef __attribute__((ext_vector_type(4))) float f32x4;

__device__ __forceinline__ void gload_lds16(const void* g, void* l) {
  __builtin_amdgcn_global_load_lds((const __attribute__((address_space(1))) void*)g,
                                   (__attribute__((address_space(3))) void*)l, 16, 0, 0);
}

// ---------------- RMSNorm (fp32 in -> bf16 out) ----------------
__global__ void rmsnorm_bf16(const float* __restrict__ x, const float* __restrict__ w,
                             __hip_bfloat16* __restrict__ out) {
  int row = blockIdx.x;
  const float* xr = x + (size_t)row * DMODEL;
  float ss = 0.f;
#pragma unroll
  for (int i = 0; i < 4; ++i) {
    float v = xr[threadIdx.x + i * 256];
    ss += v * v;
  }
#pragma unroll
  for (int off = 32; off; off >>= 1) ss += __shfl_down(ss, off, 64);
  __shared__ float wsum[4];
  int lane = threadIdx.x & 63, wid = threadIdx.x >> 6;
  if (lane == 0) wsum[wid] = ss;
  __syncthreads();
  __shared__ float s_rms;
  if (threadIdx.x == 0)
    s_rms = rsqrtf((wsum[0] + wsum[1] + wsum[2] + wsum[3]) * (1.0f / DMODEL) + 1e-6f);
  __syncthreads();
  float rms = s_rms;
  __hip_bfloat16* orow = out + (size_t)row * DMODEL;
#pragma unroll
  for (int i = 0; i < 4; ++i) {
    int c = threadIdx.x + i * 256;
    orow[c] = __float2bfloat16(xr[c] * rms * w[c]);
  }
}

// ---------------- fused weight transpose+convert (all 7 weights, 1 dispatch) ----------------
__global__ void transpose_fused(const float* __restrict__ in_proj_w,
                                const float* __restrict__ B_proj_w,
                                const float* __restrict__ C_proj_w,
                                const float* __restrict__ out_proj_w,
                                const float* __restrict__ w1,
                                const float* __restrict__ w3,
                                const float* __restrict__ w2,
                                __hip_bfloat16* __restrict__ inT,
                                __hip_bfloat16* __restrict__ BCT,
                                __hip_bfloat16* __restrict__ opT,
                                __hip_bfloat16* __restrict__ w13T,
                                __hip_bfloat16* __restrict__ w2T) {
  int id = blockIdx.x;
  const float* src; __hip_bfloat16* dst; int K, N, ilv = -1;
  if (id < 4096)       { src = in_proj_w;  dst = inT;  K = 1024; N = 4096; }
  else if (id < 4608)  { src = B_proj_w;   dst = BCT;  K = 2048; N = 256;  id -= 4096; }
  else if (id < 5120)  { src = C_proj_w;   dst = BCT + (size_t)256 * 2048; K = 2048; N = 256; id -= 4608; }
  else if (id < 7168)  { src = out_proj_w; dst = opT;  K = 2048; N = 1024; id -= 5120; }
  else if (id < 11264) { src = w1;  dst = w13T; K = 1024; N = 4096; ilv = 0;  id -= 7168; }
  else if (id < 15360) { src = w3;  dst = w13T; K = 1024; N = 4096; ilv = 16; id -= 11264; }
  else                 { src = w2;  dst = w2T;  K = 4096; N = 1024; id -= 15360; }
  int nx = N >> 5;
  int n0 = (id % nx) * 32, k0 = (id / nx) * 32;
  __shared__ float tile[32][33];
  int tx = threadIdx.x & 31, ty = threadIdx.x >> 5;
#pragma unroll
  for (int i = 0; i < 4; ++i)
    tile[ty + i * 8][tx] = src[(size_t)(k0 + ty + i * 8) * N + n0 + tx];
  __syncthreads();
#pragma unroll
  for (int i = 0; i < 4; ++i) {
    int n = n0 + ty + i * 8;
    int rp = (ilv < 0) ? n : 32 * (n >> 4) + (n & 15) + ilv;
    dst[(size_t)rp * K + k0 + tx] = __float2bfloat16(tile[tx][ty + i * 8]);
  }
}

// dt_proj_w [2048,16] -> rows 512..527 of BCT [640,2048]
__global__ void dtT_kernel(const float* __restrict__ dtW, __hip_bfloat16* __restrict__ BCT) {
  int idx = blockIdx.x * 256 + threadIdx.x;   // 0..32767
  int n = idx >> 11, k = idx & 2047;
  BCT[(size_t)(512 + n) * 2048 + k] = __float2bfloat16(dtW[(size_t)k * GG + n]);
}

// out init: out = x (fp32, float4)
__global__ void copyf4(const float4* __restrict__ src, float4* __restrict__ dst) {
  size_t idx = (size_t)blockIdx.x * 256 + threadIdx.x;
  dst[idx] = src[idx];
}

// ========= big pipelined GEMM (R11-proven, for w13): 256x256, BK=32, ring-3, frag-pipelined =========
// OUT_MODE: 1 = bf16 out, 2 = fused swiglu (interleaved WT -> bf16 [M, N/2]).
template <int OUT_MODE>
__global__ __launch_bounds__(512) void gemm_big(
    const __hip_bfloat16* __restrict__ A, const __hip_bfloat16* __restrict__ WT,
    void* __restrict__ Cout, int M, int N, int K, int nby) {
  constexpr int SLOT = 32768;
  __shared__ char smem[3 * SLOT];

  const int tid = threadIdx.x;
  const int lane = tid & 63, wid = tid >> 6;
  const int wm = wid >> 2, wn = wid & 3;
  const int lr = lane & 15, lq = lane >> 4;

  int nwg = gridDim.x, per = nwg >> 3;
  int xcd = blockIdx.x & 7, local = blockIdx.x >> 3;
  int by, bx;
  int bxl = per / nby;
  if (bxl >= 1 && bxl * nby == per) {
    int cw = 4 * bxl;
    int chunk = local / cw, wi = local % cw;
    by = chunk * 4 + (wi & 3);
    bx = xcd * bxl + (wi >> 2);
  } else {
    int g = xcd * per + local;
    by = g % nby; bx = g / nby;
  }
  int brow = by * 256, bcol = bx * 256;

  const char* Ab = (const char*)(A + (size_t)brow * K);
  const char* Bb = (const char*)(WT + (size_t)bcol * K);
  const size_t rowB = (size_t)K * 2;

  size_t gA[2], gB[2];
  int lA[2], lB[2];
#pragma unroll
  for (int i = 0; i < 2; ++i) {
    int c = i * 512 + tid;             // 0..1023
    int r = c >> 2, s = c & 3;
    size_t go = (size_t)r * rowB + (size_t)((s ^ ((r >> 1) & 3)) << 4);
    gA[i] = go; lA[i] = c * 16;
    gB[i] = go; lB[i] = 16384 + c * 16;
  }
  int offA[8], offB[4];
#pragma unroll
  for (int mf = 0; mf < 8; ++mf) {
    int row = wm * 128 + mf * 16 + lr;
    offA[mf] = row * 64 + ((lq ^ ((row >> 1) & 3)) << 4);
  }
#pragma unroll
  for (int nf = 0; nf < 4; ++nf) {
    int row = wn * 64 + nf * 16 + lr;
    offB[nf] = 16384 + row * 64 + ((lq ^ ((row >> 1) & 3)) << 4);
  }

  f32x4 acc[8][4];
#pragma unroll
  for (int m = 0; m < 8; ++m)
#pragma unroll
    for (int n = 0; n < 4; ++n) acc[m][n] = (f32x4){0.f, 0.f, 0.f, 0.f};

  auto stage = [&](int slotOff, int t) {
    char* sb = smem + slotOff;
    size_t ko = (size_t)t * 64;
#pragma unroll
    for (int i = 0; i < 2; ++i) gload_lds16(Ab + gA[i] + ko, sb + lA[i]);
#pragma unroll
    for (int i = 0; i < 2; ++i) gload_lds16(Bb + gB[i] + ko, sb + lB[i]);
  };

  const int NT = K >> 5;
  int sl0 = 0, sl1 = SLOT, sl2 = 2 * SLOT;
  stage(sl0, 0);
  stage(sl1, 1);
  asm volatile("s_waitcnt vmcnt(4)" ::: "memory");   // s0 landed
  __builtin_amdgcn_s_barrier();
  __builtin_amdgcn_sched_barrier(0);

  short8_t a[8], b[4];
#pragma unroll
  for (int mf = 0; mf < 8; ++mf) a[mf] = *(const short8_t*)(smem + sl0 + offA[mf]);
#pragma unroll
  for (int nf = 0; nf < 4; ++nf) b[nf] = *(const short8_t*)(smem + sl0 + offB[nf]);

  for (int t = 0; t < NT; ++t) {
    if (t + 2 < NT) stage(sl2, t + 2);
    __builtin_amdgcn_s_setprio(1);
#pragma unroll
    for (int mf = 0; mf < 8; ++mf)
#pragma unroll
      for (int nf = 0; nf < 4; ++nf)
        acc[mf][nf] = __builtin_amdgcn_mfma_f32_16x16x32_bf16(a[mf], b[nf], acc[mf][nf], 0, 0, 0);
    __builtin_amdgcn_s_setprio(0);

    if (t + 1 < NT) {
      if (t + 2 < NT) asm volatile("s_waitcnt vmcnt(4)" ::: "memory");
      else            asm volatile("s_waitcnt vmcnt(0)" ::: "memory");
      __builtin_amdgcn_s_barrier();
      __builtin_amdgcn_sched_barrier(0);
      const char* sp = smem + sl1;
#pragma unroll
      for (int mf = 0; mf < 8; ++mf) a[mf] = *(const short8_t*)(sp + offA[mf]);
#pragma unroll
      for (int nf = 0; nf < 4; ++nf) b[nf] = *(const short8_t*)(sp + offB[nf]);
    }
    int tmp = sl0; sl0 = sl1; sl1 = sl2; sl2 = tmp;
  }

  asm volatile("" ::: "memory");
  if constexpr (OUT_MODE == 2) {
    const int No = N >> 1;
#pragma unroll
    for (int mf = 0; mf < 8; ++mf) {
      int row0 = brow + wm * 128 + mf * 16 + lq * 4;
#pragma unroll
      for (int nfp = 0; nfp < 2; ++nfp) {
        int nf = nfp * 2;
        int col = (bcol >> 1) + wn * 32 + nfp * 16 + lr;
#pragma unroll
        for (int j = 0; j < 4; ++j) {
          float gg = acc[mf][nf][j];
          float s = gg / (1.f + expf(-gg));
          float o = s * acc[mf][nf + 1][j];
          ((__hip_bfloat16*)Cout)[(size_t)(row0 + j) * No + col] = __float2bfloat16(o);
        }
      }
    }
  } else {
#pragma unroll
    for (int mf = 0; mf < 8; ++mf) {
      int row0 = brow + wm * 128 + mf * 16 + lq * 4;
#pragma unroll
      for (int nf = 0; nf < 4; ++nf) {
        int col = bcol + wn * 64 + nf * 16 + lr;
#pragma unroll
        for (int j = 0; j < 4; ++j)
          ((__hip_bfloat16*)Cout)[(size_t)(row0 + j) * N + col] =
              __float2bfloat16(acc[mf][nf][j]);
      }
    }
  }
}

// ========= 8-phase GEMM (for in_proj): 256x256, BK=64, quadrant phases =========
template <int OUT_MODE>
__global__ __launch_bounds__(512) void gemm_big8(
    const __hip_bfloat16* __restrict__ A, const __hip_bfloat16* __restrict__ WT,
    void* __restrict__ Cout, int M, int N, int K, int nby) {
  __shared__ char smem[131072];
  const int tid = threadIdx.x;
  const int lane = tid & 63, wid = tid >> 6;
  const int wm = wid >> 2, wn = wid & 3;
  const int lr = lane & 15, lq = lane >> 4;

  int nwg = gridDim.x, per = nwg >> 3;
  int xcd = blockIdx.x & 7, local = blockIdx.x >> 3;
  int by, bx;
  int bxl = per / nby;
  if (bxl >= 1 && bxl * nby == per) {
    int cw = 4 * bxl;
    int chunk = local / cw, wi = local % cw;
    by = chunk * 4 + (wi & 3);
    bx = xcd * bxl + (wi >> 2);
  } else {
    int g = xcd * per + local;
    by = g % nby; bx = g / nby;
  }
  int brow = by * 256, bcol = bx * 256;

  const char* Ab = (const char*)(A + (size_t)brow * K);
  const char* Bb = (const char*)(WT + (size_t)bcol * K);
  const size_t rowB = (size_t)K * 2;

  size_t gOff[2];
  int lOff[2];
#pragma unroll
  for (int i = 0; i < 2; ++i) {
    int c = i * 512 + tid;
    int kkb = c >> 9, cc = c & 511;
    int r = cc >> 2, s = cc & 3;
    gOff[i] = (size_t)r * rowB + kkb * 64 + ((s ^ ((r >> 1) & 3)) << 4);
    lOff[i] = c * 16;
  }
  int offA[4][2], offB[2][2];
#pragma unroll
  for (int mf = 0; mf < 4; ++mf) {
    int r = wm * 64 + mf * 16 + lr;
    int sw = (lq << 4) ^ (((r >> 1) & 3) << 4);
    offA[mf][0] = r * 64 + sw;
    offA[mf][1] = 8192 + r * 64 + sw;
  }
#pragma unroll
  for (int nf = 0; nf < 2; ++nf) {
    int r = wn * 32 + nf * 16 + lr;
    int sw = (lq << 4) ^ (((r >> 1) & 3) << 4);
    offB[nf][0] = r * 64 + sw;
    offB[nf][1] = 8192 + r * 64 + sw;
  }

  f32x4 acc[8][4];
#pragma unroll
  for (int m = 0; m < 8; ++m)
#pragma unroll
    for (int n = 0; n < 4; ++n) acc[m][n] = (f32x4){0.f, 0.f, 0.f, 0.f};

  auto stageA = [&](int d, int h, int t) {
    char* sb = smem + d * 65536 + h * 16384;
    const char* gb = Ab + (size_t)h * 128 * rowB + (size_t)t * 128;
    gload_lds16(gb + gOff[0], sb + lOff[0]);
    gload_lds16(gb + gOff[1], sb + lOff[1]);
  };
  auto stageB = [&](int d, int h, int t) {
    char* sb = smem + d * 65536 + 32768 + h * 16384;
    const char* gb = Bb + (size_t)h * 128 * rowB + (size_t)t * 128;
    gload_lds16(gb + gOff[0], sb + lOff[0]);
    gload_lds16(gb + gOff[1], sb + lOff[1]);
  };

  const int NT = K >> 6;
  stageA(0, 0, 0); stageB(0, 0, 0);
  stageA(0, 1, 0); stageB(0, 1, 0);
  stageA(1, 0, 1); stageB(1, 0, 1);
  asm volatile("s_waitcnt vmcnt(8)" ::: "memory");
  __builtin_amdgcn_s_barrier();
  __builtin_amdgcn_sched_barrier(0);

  short8_t a[8], b0[4], b1[4];

  for (int t = 0; t < NT; ++t) {
    const int d = t & 1, e = d ^ 1;
    const char* pa0 = smem + d * 65536;
    const char* pa1 = pa0 + 16384;
    const char* pb0 = pa0 + 32768;
    const char* pb1 = pb0 + 16384;
    const bool s1 = (t + 1 < NT), s2 = (t + 2 < NT);

#pragma unroll
    for (int mf = 0; mf < 4; ++mf) {
      a[mf * 2 + 0] = *(const short8_t*)(pa0 + offA[mf][0]);
      a[mf * 2 + 1] = *(const short8_t*)(pa0 + offA[mf][1]);
    }
#pragma unroll
    for (int nf = 0; nf < 2; ++nf) {
      b0[nf * 2 + 0] = *(const short8_t*)(pb0 + offB[nf][0]);
      b0[nf * 2 + 1] = *(const short8_t*)(pb0 + offB[nf][1]);
    }
    if (s1) stageA(e, 1, t + 1);
    __builtin_amdgcn_s_barrier();
    __builtin_amdgcn_sched_barrier(0);
    __builtin_amdgcn_s_setprio(1);
#pragma unroll
    for (int mf = 0; mf < 4; ++mf)
#pragma unroll
      for (int nf = 0; nf < 2; ++nf)
#pragma unroll
        for (int kk = 0; kk < 2; ++kk)
          acc[mf][nf] = __builtin_amdgcn_mfma_f32_16x16x32_bf16(a[mf * 2 + kk], b0[nf * 2 + kk], acc[mf][nf], 0, 0, 0);
    __builtin_amdgcn_s_setprio(0);
    if (s1) asm volatile("s_waitcnt vmcnt(6)" ::: "memory");
    else    asm volatile("s_waitcnt vmcnt(0)" ::: "memory");
    __builtin_amdgcn_s_barrier();
    __builtin_amdgcn_sched_barrier(0);

#pragma unroll
    for (int nf = 0; nf < 2; ++nf) {
      b1[nf * 2 + 0] = *(const short8_t*)(pb1 + offB[nf][0]);
      b1[nf * 2 + 1] = *(const short8_t*)(pb1 + offB[nf][1]);
    }
    if (s1) stageB(e, 1, t + 1);
    __builtin_amdgcn_s_barrier();
    __builtin_amdgcn_sched_barrier(0);
    __builtin_amdgcn_s_setprio(1);
#pragma unroll
    for (int mf = 0; mf < 4; ++mf)
#pragma unroll
      for (int nf = 0; nf < 2; ++nf)
#pragma unroll
        for (int kk = 0; kk < 2; ++kk)
          acc[mf][2 + nf] = __builtin_amdgcn_mfma_f32_16x16x32_bf16(a[mf * 2 + kk], b1[nf * 2 + kk], acc[mf][2 + nf], 0, 0, 0);
    __builtin_amdgcn_s_setprio(0);
    __builtin_amdgcn_s_barrier();
    __builtin_amdgcn_sched_barrier(0);

#pragma unroll
    for (int mf = 0; mf < 4; ++mf) {
      a[mf * 2 + 0] = *(const short8_t*)(pa1 + offA[mf][0]);
      a[mf * 2 + 1] = *(const short8_t*)(pa1 + offA[mf][1]);
    }
#pragma unroll
    for (int nf = 0; nf < 2; ++nf) {
      b0[nf * 2 + 0] = *(const short8_t*)(pb0 + offB[nf][0]);
      b0[nf * 2 + 1] = *(const short8_t*)(pb0 + offB[nf][1]);
    }
    if (s2) stageA(d, 0, t + 2);
    __builtin_amdgcn_s_barrier();
    __builtin_amdgcn_sched_barrier(0);
    __builtin_amdgcn_s_setprio(1);
#pragma unroll
    for (int mf = 0; mf < 4; ++mf)
#pragma unroll
      for (int nf = 0; nf < 2; ++nf)
#pragma unroll
        for (int kk = 0; kk < 2; ++kk)
          acc[4 + mf][nf] = __builtin_amdgcn_mfma_f32_16x16x32_bf16(a[mf * 2 + kk], b0[nf * 2 + kk], acc[4 + mf][nf], 0, 0, 0);
    __builtin_amdgcn_s_setprio(0);
    __builtin_amdgcn_s_barrier();
    __builtin_amdgcn_sched_barrier(0);

#pragma unroll
    for (int nf = 0; nf < 2; ++nf) {
      b1[nf * 2 + 0] = *(const short8_t*)(pb1 + offB[nf][0]);
      b1[nf * 2 + 1] = *(const short8_t*)(pb1 + offB[nf][1]);
    }
    if (s2) stageB(d, 0, t + 2);
    __builtin_amdgcn_s_barrier();
    __builtin_amdgcn_sched_barrier(0);
    __builtin_amdgcn_s_setprio(1);
#pragma unroll
    for (int mf = 0; mf < 4; ++mf)
#pragma unroll
      for (int nf = 0; nf < 2; ++nf)
#pragma unroll
        for (int kk = 0; kk < 2; ++kk)
          acc[4 + mf][2 + nf] = __builtin_amdgcn_mfma_f32_16x16x32_bf16(a[mf * 2 + kk], b1[nf * 2 + kk], acc[4 + mf][2 + nf], 0, 0, 0);
    __builtin_amdgcn_s_setprio(0);
    if (s1) {
      if (s2) asm volatile("s_waitcnt vmcnt(8)" ::: "memory");
      else    asm volatile("s_waitcnt vmcnt(4)" ::: "memory");
      __builtin_amdgcn_s_barrier();
      __builtin_amdgcn_sched_barrier(0);
    }
  }

  asm volatile("" ::: "memory");
  if constexpr (OUT_MODE == 2) {
    const int No = N >> 1;
#pragma unroll
    for (int m = 0; m < 8; ++m) {
      int row0 = brow + (m >> 2) * 128 + wm * 64 + (m & 3) * 16 + lq * 4;
#pragma unroll
      for (int nh = 0; nh < 2; ++nh) {
        int col = (bcol >> 1) + nh * 64 + wn * 16 + lr;
#pragma unroll
        for (int j = 0; j < 4; ++j) {
          float gg = acc[m][nh * 2][j];
          float s = gg / (1.f + expf(-gg));
          float o = s * acc[m][nh * 2 + 1][j];
          ((__hip_bfloat16*)Cout)[(size_t)(row0 + j) * No + col] = __float2bfloat16(o);
        }
      }
    }
  } else {
#pragma unroll
    for (int m = 0; m < 8; ++m) {
      int row0 = brow + (m >> 2) * 128 + wm * 64 + (m & 3) * 16 + lq * 4;
#pragma unroll
      for (int n = 0; n < 4; ++n) {
        int col = bcol + (n >> 1) * 128 + wn * 32 + (n & 1) * 16 + lr;
#pragma unroll
        for (int j = 0; j < 4; ++j)
          ((__hip_bfloat16*)Cout)[(size_t)(row0 + j) * N + col] =
              __float2bfloat16(acc[m][n][j]);
      }
    }
  }
}

// ========= small pipelined GEMM (BN=128, frag-pipelined, +split-K) =========
// OUT_MODE: 0 = fp32 out (store-guarded col<nstore), 3 = fp32 atomicAdd out.
template <int OUT_MODE>
__global__ __launch_bounds__(256) void gemm_pipe(
    const __hip_bfloat16* __restrict__ A, const __hip_bfloat16* __restrict__ WT,
    void* __restrict__ Cout, int M, int N, int K, int Kstride,
    int nby, int nstore, int nsplit) {
  constexpr int SLOT = 16384;
  __shared__ char smem[3 * SLOT];

  const int tid = threadIdx.x;
  const int lane = tid & 63, wid = tid >> 6;
  const int wm = wid >> 1, wn = wid & 1;
  const int lr = lane & 15, lq = lane >> 4;

  int nper = gridDim.x / nsplit;
  int kh = blockIdx.x / nper;
  int bxid = blockIdx.x % nper;
  int per = nper >> 3;
  int xcd = bxid & 7, local = bxid >> 3;
  int by, bx;
  int bxl = per / nby;
  if (bxl >= 1 && bxl * nby == per) {
    int cw = 4 * bxl;
    int chunk = local / cw, wi = local % cw;
    by = chunk * 4 + (wi & 3);
    bx = xcd * bxl + (wi >> 2);
  } else {
    int g = xcd * per + local;
    by = g % nby; bx = g / nby;
  }
  int brow = by * 128, bcol = bx * 128;
  int koff = kh * K;

  const char* Ab = (const char*)(A + (size_t)brow * Kstride + koff);
  const char* Bb = (const char*)(WT + (size_t)bcol * Kstride + koff);
  const size_t rowB = (size_t)Kstride * 2;

  size_t gA[2], gB[2];
  int lA[2], lB[2];
#pragma unroll
  for (int i = 0; i < 2; ++i) {
    int c = i * 256 + tid;
    int r = c >> 2, s = c & 3;
    size_t go = (size_t)r * rowB + (size_t)((s ^ ((r >> 1) & 3)) << 4);
    gA[i] = go; lA[i] = c * 16;
    gB[i] = go; lB[i] = 8192 + c * 16;
  }
  int offA[4], offB[4];
#pragma unroll
  for (int mf = 0; mf < 4; ++mf) {
    int row = wm * 64 + mf * 16 + lr;
    offA[mf] = row * 64 + ((lq ^ ((row >> 1) & 3)) << 4);
  }
#pragma unroll
  for (int nf = 0; nf < 4; ++nf) {
    int row = wn * 64 + nf * 16 + lr;
    offB[nf] = 8192 + row * 64 + ((lq ^ ((row >> 1) & 3)) << 4);
  }

  f32x4 acc[4][4];
#pragma unroll
  for (int m = 0; m < 4; ++m)
#pragma unroll
    for (int n = 0; n < 4; ++n) acc[m][n] = (f32x4){0.f, 0.f, 0.f, 0.f};

  auto stage = [&](int slotOff, int t) {
    char* sb = smem + slotOff;
    size_t ko = (size_t)t * 64;
#pragma unroll
    for (int i = 0; i < 2; ++i) gload_lds16(Ab + gA[i] + ko, sb + lA[i]);
#pragma unroll
    for (int i = 0; i < 2; ++i) gload_lds16(Bb + gB[i] + ko, sb + lB[i]);
  };

  const int NT = K >> 5;
  int sl0 = 0, sl1 = SLOT, sl2 = 2 * SLOT;
  stage(sl0, 0);
  stage(sl1, 1);
  asm volatile("s_waitcnt vmcnt(4)" ::: "memory");
  __builtin_amdgcn_s_barrier();
  __builtin_amdgcn_sched_barrier(0);

  short8_t a[4], b[4];
#pragma unroll
  for (int mf = 0; mf < 4; ++mf) a[mf] = *(const short8_t*)(smem + sl0 + offA[mf]);
#pragma unroll
  for (int nf = 0; nf < 4; ++nf) b[nf] = *(const short8_t*)(smem + sl0 + offB[nf]);

  for (int t = 0; t < NT; ++t) {
    if (t + 2 < NT) stage(sl2, t + 2);
    __builtin_amdgcn_s_setprio(1);
#pragma unroll
    for (int mf = 0; mf < 4; ++mf)
#pragma unroll
      for (int nf = 0; nf < 4; ++nf)
        acc[mf][nf] = __builtin_amdgcn_mfma_f32_16x16x32_bf16(a[mf], b[nf], acc[mf][nf], 0, 0, 0);
    __builtin_amdgcn_s_setprio(0);

    if (t + 1 < NT) {
      if (t + 2 < NT) asm volatile("s_waitcnt vmcnt(4)" ::: "memory");
      else            asm volatile("s_waitcnt vmcnt(0)" ::: "memory");
      __builtin_amdgcn_s_barrier();
      __builtin_amdgcn_sched_barrier(0);
      const char* sp = smem + sl1;
#pragma unroll
      for (int mf = 0; mf < 4; ++mf) a[mf] = *(const short8_t*)(sp + offA[mf]);
#pragma unroll
      for (int nf = 0; nf < 4; ++nf) b[nf] = *(const short8_t*)(sp + offB[nf]);
    }
    int tmp = sl0; sl0 = sl1; sl1 = sl2; sl2 = tmp;
  }

  asm volatile("" ::: "memory");
#pragma unroll
  for (int mf = 0; mf < 4; ++mf) {
    int row0 = brow + wm * 64 + mf * 16 + lq * 4;
#pragma unroll
    for (int nf = 0; nf < 4; ++nf) {
      int col = bcol + wn * 64 + nf * 16 + lr;
      if (col < nstore) {
#pragma unroll
        for (int j = 0; j < 4; ++j) {
          size_t idx = (size_t)(row0 + j) * N + col;
          if constexpr (OUT_MODE == 3)
            atomicAdd(&((float*)Cout)[idx], acc[mf][nf][j]);
          else
            ((float*)Cout)[idx] = acc[mf][nf][j];
        }
      }
    }
  }
}

// ---------------- depthwise causal conv (K=7), sliding window 8 t/thread ----------------
__global__ void dwconv_bf16(const __hip_bfloat16* __restrict__ uvb, const float* __restrict__ cw,
                            __hip_bfloat16* __restrict__ vout) {
  int e = blockIdx.x * 256 + threadIdx.x;   // 0..2047
  int bt0 = blockIdx.y * 8;                  // first of 8 rows
  int t0 = bt0 & (TSEQ - 1);
  float w[7];
#pragma unroll
  for (int k = 0; k < 7; ++k) w[k] = cw[e * 7 + k];
  const __hip_bfloat16* col = uvb + (size_t)bt0 * E2 + EDIM + e;
  float win[14];
#pragma unroll
  for (int i = 0; i < 14; ++i) {
    int ts = t0 - 6 + i;
    win[i] = (ts >= 0) ? __bfloat162float(col[(i - 6) * (int)E2]) : 0.f;
  }
#pragma unroll
  for (int j = 0; j < 8; ++j) {
    float acc = 0.f;
#pragma unroll
    for (int k = 0; k < 7; ++k) acc = fmaf(w[k], win[j + k], acc);
    vout[(size_t)(bt0 + j) * EDIM + e] = __float2bfloat16(acc);
  }
}

// ---------------- chunked selective scan over BCD [BT,640] (B|C|dt) ----------------
__device__ __forceinline__ float softplus_f(float s) {
  return (s > 20.f) ? s : log1pf(expf(s));
}

__global__ void scan_phase1(const float* __restrict__ BCD, const float* __restrict__ A_log,
                            const float* __restrict__ dt_bias,
                            float* __restrict__ Pc, float* __restrict__ Sc) {
  int c = blockIdx.x >> 2, bgq = blockIdx.x & 3;
  int bg = bgq * 8 + (threadIdx.x >> 4);     // 0..31
  int b = bg >> 4, g = bg & 15, n = threadIdx.x & 15;
  int sidx = bg * 16 + n;
  float A = -expf(A_log[g * NS + n]);
  float bias = dt_bias[g];
  int t0 = c * CL;
  size_t base = (size_t)(b * TSEQ + t0) * 640;
  const float* pB = BCD + base + g * 16 + n;
  const float* pd = BCD + base + 512 + g;
  float P = 1.f, S = 0.f;
  float Bv = pB[0], rd = pd[0];
  for (int t = 0; t < CL; ++t) {
    float nB = 0.f, nd = 0.f;
    if (t + 1 < CL) { nB = pB[(size_t)(t + 1) * 640]; nd = pd[(size_t)(t + 1) * 640]; }
    float dv = softplus_f(rd + bias);
    float a = expf(dv * A);
    S = a * S + dv * Bv;
    P *= a;
    Bv = nB; rd = nd;
  }
  Pc[c * 512 + sidx] = P;
  Sc[c * 512 + sidx] = S;
}

__global__ void scan_phase2(const float* __restrict__ Pc, const float* __restrict__ Sc,
                            float* __restrict__ Init) {
  int tid = threadIdx.x;
  float s = 0.f;
  for (int c = 0; c < NCH; ++c) {
    Init[c * 512 + tid] = s;
    s = Pc[c * 512 + tid] * s + Sc[c * 512 + tid];
  }
}

// phase3 with fused gating; 256 blocks x 128 thr
__global__ void scan_phase3(const float* __restrict__ BCD, const float* __restrict__ A_log,
                            const float* __restrict__ dt_bias, const float* __restrict__ Init,
                            const __hip_bfloat16* __restrict__ uvb,
                            __hip_bfloat16* __restrict__ yg) {
  int c = blockIdx.x >> 2, bgq = blockIdx.x & 3;
  int bg = bgq * 8 + (threadIdx.x >> 4);
  int b = bg >> 4, g = bg & 15, n = threadIdx.x & 15;
  int sidx = bg * 16 + n;
  float A = -expf(A_log[g * NS + n]);
  float bias = dt_bias[g];
  int t0 = c * CL;
  size_t base = (size_t)(b * TSEQ + t0) * 640;
  const float* pB = BCD + base + g * 16 + n;
  const float* pC = pB + 256;
  const float* pd = BCD + base + 512 + g;
  float state = Init[c * 512 + sidx];
  float Bv = pB[0], Cv = pC[0], rd = pd[0];
  for (int t = 0; t < CL; ++t) {
    float nB = 0.f, nC = 0.f, nd = 0.f;
    if (t + 1 < CL) {
      size_t r = (size_t)(t + 1) * 640;
      nB = pB[r]; nC = pC[r]; nd = pd[r];
    }
    float dv = softplus_f(rd + bias);
    float a = expf(dv * A);
    state = a * state + dv * Bv;
    float p = state * Cv;
#pragma unroll
    for (int off = 8; off; off >>= 1) p += __shfl_xor(p, off, 16);
    int bt = b * TSEQ + t0 + t;
    union { short8_t v; __hip_bfloat16 h[8]; } U, O;
    U.v = *(const short8_t*)(uvb + (size_t)bt * E2 + g * 128 + n * 8);
#pragma unroll
    for (int j = 0; j < 8; ++j) {
      float u = __bfloat162float(U.h[j]);
      O.h[j] = __float2bfloat16(p / (1.f + expf(-u)));
    }
    *(short8_t*)(yg + (size_t)bt * EDIM + g * 128 + n * 8) = O.v;
    Bv = nB; Cv = nC; rd = nd;
  }
}

extern "C" void kernel_launch(void* const* d_in, const int* in_sizes, int n_in,
                              void* d_out, int out_size, void* d_ws, size_t ws_size,
                              hipStream_t stream) {
  (void)in_sizes; (void)n_in; (void)out_size; (void)ws_size;
  const float* x         = (const float*)d_in[0];
  const float* norm1_w   = (const float*)d_in[1];
  const float* in_proj_w = (const float*)d_in[2];
  const float* conv_w    = (const float*)d_in[3];
  const float* B_proj_w  = (const float*)d_in[4];
  const float* C_proj_w  = (const float*)d_in[5];
  const float* dt_proj_w = (const float*)d_in[6];
  const float* dt_proj_b = (const float*)d_in[7];
  const float* A_log     = (const float*)d_in[8];
  const float* out_proj_w= (const float*)d_in[9];
  const float* norm2_w   = (const float*)d_in[10];
  const float* w1        = (const float*)d_in[11];
  const float* w2        = (const float*)d_in[12];
  const float* w3        = (const float*)d_in[13];
  float* out = (float*)d_out;

  char* ws = (char*)d_ws;
  const size_t MB = 1024 * 1024;
  __hip_bfloat16* uvb  = (__hip_bfloat16*)(ws + 0);        // [4096,4096] 32MB; later ffb
  __hip_bfloat16* vb   = (__hip_bfloat16*)(ws + 64 * MB);  // [4096,2048] 16MB
  __hip_bfloat16* yg   = (__hip_bfloat16*)(ws + 80 * MB);  // [4096,2048] 16MB
  __hip_bfloat16* ffb  = uvb;                              // 32MB overlay (uvb dead)
  __hip_bfloat16* hb   = (__hip_bfloat16*)(ws + 96 * MB);  // [4096,1024] 8MB
  float* BCD  = (float*)(ws + 104 * MB);                   // [4096,640] fp32 = 10MB
  float* Pc   = (float*)(ws + 114 * MB);                   // 128KB
  float* Sc   = (float*)(ws + 114 * MB + 128 * 1024);      // 128KB
  float* Init = (float*)(ws + 114 * MB + 256 * 1024);      // 128KB
  __hip_bfloat16* inT  = (__hip_bfloat16*)(ws + 115 * MB); // [4096,1024] 8MB
  __hip_bfloat16* BCT  = (__hip_bfloat16*)(ws + 123 * MB); // [640,2048] 2.5MB
  __hip_bfloat16* opT  = (__hip_bfloat16*)(ws + 126 * MB); // [1024,2048] 4MB
  __hip_bfloat16* w13T = (__hip_bfloat16*)(ws + 130 * MB); // [8192,1024] 16MB (ilv)
  __hip_bfloat16* w2T  = (__hip_bfloat16*)(ws + 146 * MB); // [1024,4096] 8MB

  // 0) weight transposes (1 dispatch) + dt row
  transpose_fused<<<19456, 256, 0, stream>>>(in_proj_w, B_proj_w, C_proj_w, out_proj_w,
                                             w1, w3, w2, inT, BCT, opT, w13T, w2T);
  dtT_kernel<<<128, 256, 0, stream>>>(dt_proj_w, BCT);

  // 1) hb = rmsnorm(x)
  rmsnorm_bf16<<<BT, 256, 0, stream>>>(x, norm1_w, hb);
  // 2) uvb = hb @ in_proj  (8-phase, 256 blocks)
  gemm_big8<1><<<256, 512, 0, stream>>>(hb, inT, uvb, BT, E2, DMODEL, 16);
  // 3) vb = causal dwconv(uvb[:, E:2E])
  dwconv_bf16<<<dim3(EDIM / 256, BT / 8), 256, 0, stream>>>(uvb, conv_w, vb);
  // 4) BCD = vb @ [B|C|dt] (N=640, store cols<528, non-split)
  gemm_pipe<0><<<160, 256, 0, stream>>>(vb, BCT, BCD, BT, 640, 2048, 2048, 32, 528, 1);
  // 5) chunked scan -> phase3 writes gated yg directly
  scan_phase1<<<NCH * 4, 128, 0, stream>>>(BCD, A_log, dt_proj_b, Pc, Sc);
  scan_phase2<<<1, 512, 0, stream>>>(Pc, Sc, Init);
  scan_phase3<<<NCH * 4, 128, 0, stream>>>(BCD, A_log, dt_proj_b, Init, uvb, yg);
  // 6) out = x; out += yg @ out_proj (split-K=2, atomic epilogue)
  copyf4<<<(BT * DMODEL / 4) / 256, 256, 0, stream>>>((const float4*)x, (float4*)out);
  gemm_pipe<3><<<512, 256, 0, stream>>>(yg, opT, out, BT, DMODEL, 1024, EDIM, 32, DMODEL, 2);
  // 7) hb = rmsnorm(out)
  rmsnorm_bf16<<<BT, 256, 0, stream>>>(out, norm2_w, hb);
  // 8) ffb = swiglu(hb @ [w1|w3 ilv])  (frag-pipelined gemm_big, 512 blocks)
  gemm_big<2><<<512, 512, 0, stream>>>(hb, w13T, ffb, BT, 8192, DMODEL, 16);
  // 9) out += ffb @ w2 (split-K=2, atomic epilogue)
  gemm_pipe<3><<<512, 256, 0, stream>>>(ffb, w2T, out, BT, DMODEL, 2048, DFF, 32, DMODEL, 2);
}

// Round 15
// 352.310 us; speedup vs baseline: 1.0396x; 1.0396x over previous
//
#include <hip/hip_runtime.h>
#include <hip/hip_bf16.h>
#include <math.h>

// Problem dims (fixed)
#define BT    4096     // B*T rows
#define TSEQ  2048
#define DMODEL 1024
#define EDIM  2048
#define E2    4096     // 2*E
#define GG    16       // groups
#define NS    16       // state
#define DFF   4096
#define NCH   64       // scan chunks
#define CL    32       // chunk length (NCH*CL == TSEQ)

typedef __attribute__((ext_vector_type(8))) short short8_t;
typedef __attribute__((ext_vector_type(4))) float f32x4;

__device__ __forceinline__ void gload_lds16(const void* g, void* l) {
  __builtin_amdgcn_global_load_lds((const __attribute__((address_space(1))) void*)g,
                                   (__attribute__((address_space(3))) void*)l, 16, 0, 0);
}

// ---------------- RMSNorm (fp32 in -> bf16 out) ----------------
__global__ void rmsnorm_bf16(const float* __restrict__ x, const float* __restrict__ w,
                             __hip_bfloat16* __restrict__ out) {
  int row = blockIdx.x;
  const float* xr = x + (size_t)row * DMODEL;
  float ss = 0.f;
#pragma unroll
  for (int i = 0; i < 4; ++i) {
    float v = xr[threadIdx.x + i * 256];
    ss += v * v;
  }
#pragma unroll
  for (int off = 32; off; off >>= 1) ss += __shfl_down(ss, off, 64);
  __shared__ float wsum[4];
  int lane = threadIdx.x & 63, wid = threadIdx.x >> 6;
  if (lane == 0) wsum[wid] = ss;
  __syncthreads();
  __shared__ float s_rms;
  if (threadIdx.x == 0)
    s_rms = rsqrtf((wsum[0] + wsum[1] + wsum[2] + wsum[3]) * (1.0f / DMODEL) + 1e-6f);
  __syncthreads();
  float rms = s_rms;
  __hip_bfloat16* orow = out + (size_t)row * DMODEL;
#pragma unroll
  for (int i = 0; i < 4; ++i) {
    int c = threadIdx.x + i * 256;
    orow[c] = __float2bfloat16(xr[c] * rms * w[c]);
  }
}

// ---------------- fused weight transpose+convert (7 weights + dt row, 1 dispatch) ----------------
// tiles: in_proj [0,4096) | B [4096,4608) | C [4608,5120) | out_proj [5120,7168)
//        w1-ilv [7168,11264) | w3-ilv [11264,15360) | w2 [15360,19456) | dt [19456,19584)
__global__ void transpose_fused(const float* __restrict__ in_proj_w,
                                const float* __restrict__ B_proj_w,
                                const float* __restrict__ C_proj_w,
                                const float* __restrict__ out_proj_w,
                                const float* __restrict__ w1,
                                const float* __restrict__ w3,
                                const float* __restrict__ w2,
                                const float* __restrict__ dtW,
                                __hip_bfloat16* __restrict__ inT,
                                __hip_bfloat16* __restrict__ BCT,
                                __hip_bfloat16* __restrict__ opT,
                                __hip_bfloat16* __restrict__ w13T,
                                __hip_bfloat16* __restrict__ w2T) {
  int id = blockIdx.x;
  if (id >= 19456) {
    int idx = (id - 19456) * 256 + threadIdx.x;   // 0..32767
    int n = idx >> 11, k = idx & 2047;
    BCT[(size_t)(512 + n) * 2048 + k] = __float2bfloat16(dtW[(size_t)k * GG + n]);
    return;
  }
  const float* src; __hip_bfloat16* dst; int K, N, ilv = -1;
  if (id < 4096)       { src = in_proj_w;  dst = inT;  K = 1024; N = 4096; }
  else if (id < 4608)  { src = B_proj_w;   dst = BCT;  K = 2048; N = 256;  id -= 4096; }
  else if (id < 5120)  { src = C_proj_w;   dst = BCT + (size_t)256 * 2048; K = 2048; N = 256; id -= 4608; }
  else if (id < 7168)  { src = out_proj_w; dst = opT;  K = 2048; N = 1024; id -= 5120; }
  else if (id < 11264) { src = w1;  dst = w13T; K = 1024; N = 4096; ilv = 0;  id -= 7168; }
  else if (id < 15360) { src = w3;  dst = w13T; K = 1024; N = 4096; ilv = 16; id -= 11264; }
  else                 { src = w2;  dst = w2T;  K = 4096; N = 1024; id -= 15360; }
  int nx = N >> 5;
  int n0 = (id % nx) * 32, k0 = (id / nx) * 32;
  __shared__ float tile[32][33];
  int tx = threadIdx.x & 31, ty = threadIdx.x >> 5;
#pragma unroll
  for (int i = 0; i < 4; ++i)
    tile[ty + i * 8][tx] = src[(size_t)(k0 + ty + i * 8) * N + n0 + tx];
  __syncthreads();
#pragma unroll
  for (int i = 0; i < 4; ++i) {
    int n = n0 + ty + i * 8;
    int rp = (ilv < 0) ? n : 32 * (n >> 4) + (n & 15) + ilv;
    dst[(size_t)rp * K + k0 + tx] = __float2bfloat16(tile[tx][ty + i * 8]);
  }
}

// out init: out = x (fp32, float4)
__global__ void copyf4(const float4* __restrict__ src, float4* __restrict__ dst) {
  size_t idx = (size_t)blockIdx.x * 256 + threadIdx.x;
  dst[idx] = src[idx];
}

// ========= 8-phase GEMM (for in_proj AND w13 -- the measured-355 config) =========
// 256x256, BK=64, quadrant phases, counted vmcnt (6/8), never 0 mid-loop.
// OUT_MODE: 1 = bf16 out, 2 = fused swiglu (interleaved WT -> bf16 [M,N/2]).
template <int OUT_MODE>
__global__ __launch_bounds__(512) void gemm_big8(
    const __hip_bfloat16* __restrict__ A, const __hip_bfloat16* __restrict__ WT,
    void* __restrict__ Cout, int M, int N, int K, int nby) {
  __shared__ char smem[131072];
  const int tid = threadIdx.x;
  const int lane = tid & 63, wid = tid >> 6;
  const int wm = wid >> 2, wn = wid & 3;
  const int lr = lane & 15, lq = lane >> 4;

  int nwg = gridDim.x, per = nwg >> 3;
  int xcd = blockIdx.x & 7, local = blockIdx.x >> 3;
  int by, bx;
  int bxl = per / nby;
  if (bxl >= 1 && bxl * nby == per) {
    int cw = 4 * bxl;
    int chunk = local / cw, wi = local % cw;
    by = chunk * 4 + (wi & 3);
    bx = xcd * bxl + (wi >> 2);
  } else {
    int g = xcd * per + local;
    by = g % nby; bx = g / nby;
  }
  int brow = by * 256, bcol = bx * 256;

  const char* Ab = (const char*)(A + (size_t)brow * K);
  const char* Bb = (const char*)(WT + (size_t)bcol * K);
  const size_t rowB = (size_t)K * 2;

  size_t gOff[2];
  int lOff[2];
#pragma unroll
  for (int i = 0; i < 2; ++i) {
    int c = i * 512 + tid;
    int kkb = c >> 9, cc = c & 511;
    int r = cc >> 2, s = cc & 3;
    gOff[i] = (size_t)r * rowB + kkb * 64 + ((s ^ ((r >> 1) & 3)) << 4);
    lOff[i] = c * 16;
  }
  int offA[4][2], offB[2][2];
#pragma unroll
  for (int mf = 0; mf < 4; ++mf) {
    int r = wm * 64 + mf * 16 + lr;
    int sw = (lq << 4) ^ (((r >> 1) & 3) << 4);
    offA[mf][0] = r * 64 + sw;
    offA[mf][1] = 8192 + r * 64 + sw;
  }
#pragma unroll
  for (int nf = 0; nf < 2; ++nf) {
    int r = wn * 32 + nf * 16 + lr;
    int sw = (lq << 4) ^ (((r >> 1) & 3) << 4);
    offB[nf][0] = r * 64 + sw;
    offB[nf][1] = 8192 + r * 64 + sw;
  }

  f32x4 acc[8][4];
#pragma unroll
  for (int m = 0; m < 8; ++m)
#pragma unroll
    for (int n = 0; n < 4; ++n) acc[m][n] = (f32x4){0.f, 0.f, 0.f, 0.f};

  auto stageA = [&](int d, int h, int t) {
    char* sb = smem + d * 65536 + h * 16384;
    const char* gb = Ab + (size_t)h * 128 * rowB + (size_t)t * 128;
    gload_lds16(gb + gOff[0], sb + lOff[0]);
    gload_lds16(gb + gOff[1], sb + lOff[1]);
  };
  auto stageB = [&](int d, int h, int t) {
    char* sb = smem + d * 65536 + 32768 + h * 16384;
    const char* gb = Bb + (size_t)h * 128 * rowB + (size_t)t * 128;
    gload_lds16(gb + gOff[0], sb + lOff[0]);
    gload_lds16(gb + gOff[1], sb + lOff[1]);
  };

  const int NT = K >> 6;
  stageA(0, 0, 0); stageB(0, 0, 0);
  stageA(0, 1, 0); stageB(0, 1, 0);
  stageA(1, 0, 1); stageB(1, 0, 1);
  asm volatile("s_waitcnt vmcnt(8)" ::: "memory");
  __builtin_amdgcn_s_barrier();
  __builtin_amdgcn_sched_barrier(0);

  short8_t a[8], b0[4], b1[4];

  for (int t = 0; t < NT; ++t) {
    const int d = t & 1, e = d ^ 1;
    const char* pa0 = smem + d * 65536;
    const char* pa1 = pa0 + 16384;
    const char* pb0 = pa0 + 32768;
    const char* pb1 = pb0 + 16384;
    const bool s1 = (t + 1 < NT), s2 = (t + 2 < NT);

    // ---- phase 0: quadrant (mh=0, nh=0) ----
#pragma unroll
    for (int mf = 0; mf < 4; ++mf) {
      a[mf * 2 + 0] = *(const short8_t*)(pa0 + offA[mf][0]);
      a[mf * 2 + 1] = *(const short8_t*)(pa0 + offA[mf][1]);
    }
#pragma unroll
    for (int nf = 0; nf < 2; ++nf) {
      b0[nf * 2 + 0] = *(const short8_t*)(pb0 + offB[nf][0]);
      b0[nf * 2 + 1] = *(const short8_t*)(pb0 + offB[nf][1]);
    }
    if (s1) stageA(e, 1, t + 1);
    __builtin_amdgcn_s_barrier();
    __builtin_amdgcn_sched_barrier(0);
    __builtin_amdgcn_s_setprio(1);
#pragma unroll
    for (int mf = 0; mf < 4; ++mf)
#pragma unroll
      for (int nf = 0; nf < 2; ++nf)
#pragma unroll
        for (int kk = 0; kk < 2; ++kk)
          acc[mf][nf] = __builtin_amdgcn_mfma_f32_16x16x32_bf16(a[mf * 2 + kk], b0[nf * 2 + kk], acc[mf][nf], 0, 0, 0);
    __builtin_amdgcn_s_setprio(0);
    if (s1) asm volatile("s_waitcnt vmcnt(6)" ::: "memory");
    else    asm volatile("s_waitcnt vmcnt(0)" ::: "memory");
    __builtin_amdgcn_s_barrier();
    __builtin_amdgcn_sched_barrier(0);

    // ---- phase 1: quadrant (mh=0, nh=1), A reused ----
#pragma unroll
    for (int nf = 0; nf < 2; ++nf) {
      b1[nf * 2 + 0] = *(const short8_t*)(pb1 + offB[nf][0]);
      b1[nf * 2 + 1] = *(const short8_t*)(pb1 + offB[nf][1]);
    }
    if (s1) stageB(e, 1, t + 1);
    __builtin_amdgcn_s_barrier();
    __builtin_amdgcn_sched_barrier(0);
    __builtin_amdgcn_s_setprio(1);
#pragma unroll
    for (int mf = 0; mf < 4; ++mf)
#pragma unroll
      for (int nf = 0; nf < 2; ++nf)
#pragma unroll
        for (int kk = 0; kk < 2; ++kk)
          acc[mf][2 + nf] = __builtin_amdgcn_mfma_f32_16x16x32_bf16(a[mf * 2 + kk], b1[nf * 2 + kk], acc[mf][2 + nf], 0, 0, 0);
    __builtin_amdgcn_s_setprio(0);
    __builtin_amdgcn_s_barrier();
    __builtin_amdgcn_sched_barrier(0);

    // ---- phase 2: quadrant (mh=1, nh=0) ----
#pragma unroll
    for (int mf = 0; mf < 4; ++mf) {
      a[mf * 2 + 0] = *(const short8_t*)(pa1 + offA[mf][0]);
      a[mf * 2 + 1] = *(const short8_t*)(pa1 + offA[mf][1]);
    }
#pragma unroll
    for (int nf = 0; nf < 2; ++nf) {
      b0[nf * 2 + 0] = *(const short8_t*)(pb0 + offB[nf][0]);
      b0[nf * 2 + 1] = *(const short8_t*)(pb0 + offB[nf][1]);
    }
    if (s2) stageA(d, 0, t + 2);
    __builtin_amdgcn_s_barrier();
    __builtin_amdgcn_sched_barrier(0);
    __builtin_amdgcn_s_setprio(1);
#pragma unroll
    for (int mf = 0; mf < 4; ++mf)
#pragma unroll
      for (int nf = 0; nf < 2; ++nf)
#pragma unroll
        for (int kk = 0; kk < 2; ++kk)
          acc[4 + mf][nf] = __builtin_amdgcn_mfma_f32_16x16x32_bf16(a[mf * 2 + kk], b0[nf * 2 + kk], acc[4 + mf][nf], 0, 0, 0);
    __builtin_amdgcn_s_setprio(0);
    __builtin_amdgcn_s_barrier();
    __builtin_amdgcn_sched_barrier(0);

    // ---- phase 3: quadrant (mh=1, nh=1) ----
#pragma unroll
    for (int nf = 0; nf < 2; ++nf) {
      b1[nf * 2 + 0] = *(const short8_t*)(pb1 + offB[nf][0]);
      b1[nf * 2 + 1] = *(const short8_t*)(pb1 + offB[nf][1]);
    }
    if (s2) stageB(d, 0, t + 2);
    __builtin_amdgcn_s_barrier();
    __builtin_amdgcn_sched_barrier(0);
    __builtin_amdgcn_s_setprio(1);
#pragma unroll
    for (int mf = 0; mf < 4; ++mf)
#pragma unroll
      for (int nf = 0; nf < 2; ++nf)
#pragma unroll
        for (int kk = 0; kk < 2; ++kk)
          acc[4 + mf][2 + nf] = __builtin_amdgcn_mfma_f32_16x16x32_bf16(a[mf * 2 + kk], b1[nf * 2 + kk], acc[4 + mf][2 + nf], 0, 0, 0);
    __builtin_amdgcn_s_setprio(0);
    if (s1) {
      if (s2) asm volatile("s_waitcnt vmcnt(8)" ::: "memory");
      else    asm volatile("s_waitcnt vmcnt(4)" ::: "memory");
      __builtin_amdgcn_s_barrier();
      __builtin_amdgcn_sched_barrier(0);
    }
  }

  asm volatile("" ::: "memory");
  if constexpr (OUT_MODE == 2) {
    const int No = N >> 1;
#pragma unroll
    for (int m = 0; m < 8; ++m) {
      int row0 = brow + (m >> 2) * 128 + wm * 64 + (m & 3) * 16 + lq * 4;
#pragma unroll
      for (int nh = 0; nh < 2; ++nh) {
        int col = (bcol >> 1) + nh * 64 + wn * 16 + lr;
#pragma unroll
        for (int j = 0; j < 4; ++j) {
          float gg = acc[m][nh * 2][j];
          float s = gg / (1.f + expf(-gg));
          float o = s * acc[m][nh * 2 + 1][j];
          ((__hip_bfloat16*)Cout)[(size_t)(row0 + j) * No + col] = __float2bfloat16(o);
        }
      }
    }
  } else {
#pragma unroll
    for (int m = 0; m < 8; ++m) {
      int row0 = brow + (m >> 2) * 128 + wm * 64 + (m & 3) * 16 + lq * 4;
#pragma unroll
      for (int n = 0; n < 4; ++n) {
        int col = bcol + (n >> 1) * 128 + wn * 32 + (n & 1) * 16 + lr;
#pragma unroll
        for (int j = 0; j < 4; ++j)
          ((__hip_bfloat16*)Cout)[(size_t)(row0 + j) * N + col] =
              __float2bfloat16(acc[m][n][j]);
      }
    }
  }
}

// ========= small pipelined GEMM (BN=128, frag-pipelined, +split-K) =========
// OUT_MODE: 0 = fp32 out (store-guarded col<nstore), 3 = fp32 atomicAdd out.
template <int OUT_MODE>
__global__ __launch_bounds__(256) void gemm_pipe(
    const __hip_bfloat16* __restrict__ A, const __hip_bfloat16* __restrict__ WT,
    void* __restrict__ Cout, int M, int N, int K, int Kstride,
    int nby, int nstore, int nsplit) {
  constexpr int SLOT = 16384;
  __shared__ char smem[3 * SLOT];

  const int tid = threadIdx.x;
  const int lane = tid & 63, wid = tid >> 6;
  const int wm = wid >> 1, wn = wid & 1;
  const int lr = lane & 15, lq = lane >> 4;

  int nper = gridDim.x / nsplit;
  int kh = blockIdx.x / nper;
  int bxid = blockIdx.x % nper;
  int per = nper >> 3;
  int xcd = bxid & 7, local = bxid >> 3;
  int by, bx;
  int bxl = per / nby;
  if (bxl >= 1 && bxl * nby == per) {
    int cw = 4 * bxl;
    int chunk = local / cw, wi = local % cw;
    by = chunk * 4 + (wi & 3);
    bx = xcd * bxl + (wi >> 2);
  } else {
    int g = xcd * per + local;
    by = g % nby; bx = g / nby;
  }
  int brow = by * 128, bcol = bx * 128;
  int koff = kh * K;

  const char* Ab = (const char*)(A + (size_t)brow * Kstride + koff);
  const char* Bb = (const char*)(WT + (size_t)bcol * Kstride + koff);
  const size_t rowB = (size_t)Kstride * 2;

  size_t gA[2], gB[2];
  int lA[2], lB[2];
#pragma unroll
  for (int i = 0; i < 2; ++i) {
    int c = i * 256 + tid;
    int r = c >> 2, s = c & 3;
    size_t go = (size_t)r * rowB + (size_t)((s ^ ((r >> 1) & 3)) << 4);
    gA[i] = go; lA[i] = c * 16;
    gB[i] = go; lB[i] = 8192 + c * 16;
  }
  int offA[4], offB[4];
#pragma unroll
  for (int mf = 0; mf < 4; ++mf) {
    int row = wm * 64 + mf * 16 + lr;
    offA[mf] = row * 64 + ((lq ^ ((row >> 1) & 3)) << 4);
  }
#pragma unroll
  for (int nf = 0; nf < 4; ++nf) {
    int row = wn * 64 + nf * 16 + lr;
    offB[nf] = 8192 + row * 64 + ((lq ^ ((row >> 1) & 3)) << 4);
  }

  f32x4 acc[4][4];
#pragma unroll
  for (int m = 0; m < 4; ++m)
#pragma unroll
    for (int n = 0; n < 4; ++n) acc[m][n] = (f32x4){0.f, 0.f, 0.f, 0.f};

  auto stage = [&](int slotOff, int t) {
    char* sb = smem + slotOff;
    size_t ko = (size_t)t * 64;
#pragma unroll
    for (int i = 0; i < 2; ++i) gload_lds16(Ab + gA[i] + ko, sb + lA[i]);
#pragma unroll
    for (int i = 0; i < 2; ++i) gload_lds16(Bb + gB[i] + ko, sb + lB[i]);
  };

  const int NT = K >> 5;
  int sl0 = 0, sl1 = SLOT, sl2 = 2 * SLOT;
  stage(sl0, 0);
  stage(sl1, 1);
  asm volatile("s_waitcnt vmcnt(4)" ::: "memory");
  __builtin_amdgcn_s_barrier();
  __builtin_amdgcn_sched_barrier(0);

  short8_t a[4], b[4];
#pragma unroll
  for (int mf = 0; mf < 4; ++mf) a[mf] = *(const short8_t*)(smem + sl0 + offA[mf]);
#pragma unroll
  for (int nf = 0; nf < 4; ++nf) b[nf] = *(const short8_t*)(smem + sl0 + offB[nf]);

  for (int t = 0; t < NT; ++t) {
    if (t + 2 < NT) stage(sl2, t + 2);
    __builtin_amdgcn_s_setprio(1);
#pragma unroll
    for (int mf = 0; mf < 4; ++mf)
#pragma unroll
      for (int nf = 0; nf < 4; ++nf)
        acc[mf][nf] = __builtin_amdgcn_mfma_f32_16x16x32_bf16(a[mf], b[nf], acc[mf][nf], 0, 0, 0);
    __builtin_amdgcn_s_setprio(0);

    if (t + 1 < NT) {
      if (t + 2 < NT) asm volatile("s_waitcnt vmcnt(4)" ::: "memory");
      else            asm volatile("s_waitcnt vmcnt(0)" ::: "memory");
      __builtin_amdgcn_s_barrier();
      __builtin_amdgcn_sched_barrier(0);
      const char* sp = smem + sl1;
#pragma unroll
      for (int mf = 0; mf < 4; ++mf) a[mf] = *(const short8_t*)(sp + offA[mf]);
#pragma unroll
      for (int nf = 0; nf < 4; ++nf) b[nf] = *(const short8_t*)(sp + offB[nf]);
    }
    int tmp = sl0; sl0 = sl1; sl1 = sl2; sl2 = tmp;
  }

  asm volatile("" ::: "memory");
#pragma unroll
  for (int mf = 0; mf < 4; ++mf) {
    int row0 = brow + wm * 64 + mf * 16 + lq * 4;
#pragma unroll
    for (int nf = 0; nf < 4; ++nf) {
      int col = bcol + wn * 64 + nf * 16 + lr;
      if (col < nstore) {
#pragma unroll
        for (int j = 0; j < 4; ++j) {
          size_t idx = (size_t)(row0 + j) * N + col;
          if constexpr (OUT_MODE == 3)
            atomicAdd(&((float*)Cout)[idx], acc[mf][nf][j]);
          else
            ((float*)Cout)[idx] = acc[mf][nf][j];
        }
      }
    }
  }
}

// ---------------- depthwise causal conv (K=7), sliding window 8 t/thread ----------------
__global__ void dwconv_bf16(const __hip_bfloat16* __restrict__ uvb, const float* __restrict__ cw,
                            __hip_bfloat16* __restrict__ vout) {
  int e = blockIdx.x * 256 + threadIdx.x;   // 0..2047
  int bt0 = blockIdx.y * 8;                  // first of 8 rows
  int t0 = bt0 & (TSEQ - 1);
  float w[7];
#pragma unroll
  for (int k = 0; k < 7; ++k) w[k] = cw[e * 7 + k];
  const __hip_bfloat16* col = uvb + (size_t)bt0 * E2 + EDIM + e;
  float win[14];
#pragma unroll
  for (int i = 0; i < 14; ++i) {
    int ts = t0 - 6 + i;
    win[i] = (ts >= 0) ? __bfloat162float(col[(i - 6) * (int)E2]) : 0.f;
  }
#pragma unroll
  for (int j = 0; j < 8; ++j) {
    float acc = 0.f;
#pragma unroll
    for (int k = 0; k < 7; ++k) acc = fmaf(w[k], win[j + k], acc);
    vout[(size_t)(bt0 + j) * EDIM + e] = __float2bfloat16(acc);
  }
}

// ---------------- chunked selective scan over BCD [BT,640] (B|C|dt) ----------------
__device__ __forceinline__ float softplus_f(float s) {
  return (s > 20.f) ? s : log1pf(expf(s));
}

__global__ void scan_phase1(const float* __restrict__ BCD, const float* __restrict__ A_log,
                            const float* __restrict__ dt_bias,
                            float* __restrict__ Pc, float* __restrict__ Sc) {
  int c = blockIdx.x >> 2, bgq = blockIdx.x & 3;
  int bg = bgq * 8 + (threadIdx.x >> 4);     // 0..31
  int b = bg >> 4, g = bg & 15, n = threadIdx.x & 15;
  int sidx = bg * 16 + n;
  float A = -expf(A_log[g * NS + n]);
  float bias = dt_bias[g];
  int t0 = c * CL;
  size_t base = (size_t)(b * TSEQ + t0) * 640;
  const float* pB = BCD + base + g * 16 + n;
  const float* pd = BCD + base + 512 + g;
  float P = 1.f, S = 0.f;
  float Bv = pB[0], rd = pd[0];
  for (int t = 0; t < CL; ++t) {
    float nB = 0.f, nd = 0.f;
    if (t + 1 < CL) { nB = pB[(size_t)(t + 1) * 640]; nd = pd[(size_t)(t + 1) * 640]; }
    float dv = softplus_f(rd + bias);
    float a = expf(dv * A);
    S = a * S + dv * Bv;
    P *= a;
    Bv = nB; rd = nd;
  }
  Pc[c * 512 + sidx] = P;
  Sc[c * 512 + sidx] = S;
}

__global__ void scan_phase2(const float* __restrict__ Pc, const float* __restrict__ Sc,
                            float* __restrict__ Init) {
  int tid = threadIdx.x;
  float s = 0.f;
  for (int c = 0; c < NCH; ++c) {
    Init[c * 512 + tid] = s;
    s = Pc[c * 512 + tid] * s + Sc[c * 512 + tid];
  }
}

// phase3 with fused gating; 256 blocks x 128 thr
__global__ void scan_phase3(const float* __restrict__ BCD, const float* __restrict__ A_log,
                            const float* __restrict__ dt_bias, const float* __restrict__ Init,
                            const __hip_bfloat16* __restrict__ uvb,
                            __hip_bfloat16* __restrict__ yg) {
  int c = blockIdx.x >> 2, bgq = blockIdx.x & 3;
  int bg = bgq * 8 + (threadIdx.x >> 4);
  int b = bg >> 4, g = bg & 15, n = threadIdx.x & 15;
  int sidx = bg * 16 + n;
  float A = -expf(A_log[g * NS + n]);
  float bias = dt_bias[g];
  int t0 = c * CL;
  size_t base = (size_t)(b * TSEQ + t0) * 640;
  const float* pB = BCD + base + g * 16 + n;
  const float* pC = pB + 256;
  const float* pd = BCD + base + 512 + g;
  float state = Init[c * 512 + sidx];
  float Bv = pB[0], Cv = pC[0], rd = pd[0];
  for (int t = 0; t < CL; ++t) {
    float nB = 0.f, nC = 0.f, nd = 0.f;
    if (t + 1 < CL) {
      size_t r = (size_t)(t + 1) * 640;
      nB = pB[r]; nC = pC[r]; nd = pd[r];
    }
    float dv = softplus_f(rd + bias);
    float a = expf(dv * A);
    state = a * state + dv * Bv;
    float p = state * Cv;
#pragma unroll
    for (int off = 8; off; off >>= 1) p += __shfl_xor(p, off, 16);
    int bt = b * TSEQ + t0 + t;
    union { short8_t v; __hip_bfloat16 h[8]; } U, O;
    U.v = *(const short8_t*)(uvb + (size_t)bt * E2 + g * 128 + n * 8);
#pragma unroll
    for (int j = 0; j < 8; ++j) {
      float u = __bfloat162float(U.h[j]);
      O.h[j] = __float2bfloat16(p / (1.f + expf(-u)));
    }
    *(short8_t*)(yg + (size_t)bt * EDIM + g * 128 + n * 8) = O.v;
    Bv = nB; Cv = nC; rd = nd;
  }
}

extern "C" void kernel_launch(void* const* d_in, const int* in_sizes, int n_in,
                              void* d_out, int out_size, void* d_ws, size_t ws_size,
                              hipStream_t stream) {
  (void)in_sizes; (void)n_in; (void)out_size; (void)ws_size;
  const float* x         = (const float*)d_in[0];
  const float* norm1_w   = (const float*)d_in[1];
  const float* in_proj_w = (const float*)d_in[2];
  const float* conv_w    = (const float*)d_in[3];
  const float* B_proj_w  = (const float*)d_in[4];
  const float* C_proj_w  = (const float*)d_in[5];
  const float* dt_proj_w = (const float*)d_in[6];
  const float* dt_proj_b = (const float*)d_in[7];
  const float* A_log     = (const float*)d_in[8];
  const float* out_proj_w= (const float*)d_in[9];
  const float* norm2_w   = (const float*)d_in[10];
  const float* w1        = (const float*)d_in[11];
  const float* w2        = (const float*)d_in[12];
  const float* w3        = (const float*)d_in[13];
  float* out = (float*)d_out;

  char* ws = (char*)d_ws;
  const size_t MB = 1024 * 1024;
  __hip_bfloat16* uvb  = (__hip_bfloat16*)(ws + 0);        // [4096,4096] 32MB; later ffb
  __hip_bfloat16* vb   = (__hip_bfloat16*)(ws + 64 * MB);  // [4096,2048] 16MB
  __hip_bfloat16* yg   = (__hip_bfloat16*)(ws + 80 * MB);  // [4096,2048] 16MB
  __hip_bfloat16* ffb  = uvb;                              // 32MB overlay (uvb dead)
  __hip_bfloat16* hb   = (__hip_bfloat16*)(ws + 96 * MB);  // [4096,1024] 8MB
  float* BCD  = (float*)(ws + 104 * MB);                   // [4096,640] fp32 = 10MB
  float* Pc   = (float*)(ws + 114 * MB);                   // 128KB
  float* Sc   = (float*)(ws + 114 * MB + 128 * 1024);      // 128KB
  float* Init = (float*)(ws + 114 * MB + 256 * 1024);      // 128KB
  __hip_bfloat16* inT  = (__hip_bfloat16*)(ws + 115 * MB); // [4096,1024] 8MB
  __hip_bfloat16* BCT  = (__hip_bfloat16*)(ws + 123 * MB); // [640,2048] 2.5MB
  __hip_bfloat16* opT  = (__hip_bfloat16*)(ws + 126 * MB); // [1024,2048] 4MB
  __hip_bfloat16* w13T = (__hip_bfloat16*)(ws + 130 * MB); // [8192,1024] 16MB (ilv)
  __hip_bfloat16* w2T  = (__hip_bfloat16*)(ws + 146 * MB); // [1024,4096] 8MB

  // 0) weight transposes + dt row (1 dispatch)
  transpose_fused<<<19584, 256, 0, stream>>>(in_proj_w, B_proj_w, C_proj_w, out_proj_w,
                                             w1, w3, w2, dt_proj_w,
                                             inT, BCT, opT, w13T, w2T);

  // 1) hb = rmsnorm(x)
  rmsnorm_bf16<<<BT, 256, 0, stream>>>(x, norm1_w, hb);
  // 2) uvb = hb @ in_proj  (8-phase, 256 blocks)
  gemm_big8<1><<<256, 512, 0, stream>>>(hb, inT, uvb, BT, E2, DMODEL, 16);
  // 3) vb = causal dwconv(uvb[:, E:2E])
  dwconv_bf16<<<dim3(EDIM / 256, BT / 8), 256, 0, stream>>>(uvb, conv_w, vb);
  // 4) BCD = vb @ [B|C|dt] (N=640, store cols<528, non-split)
  gemm_pipe<0><<<160, 256, 0, stream>>>(vb, BCT, BCD, BT, 640, 2048, 2048, 32, 528, 1);
  // 5) chunked scan -> phase3 writes gated yg directly
  scan_phase1<<<NCH * 4, 128, 0, stream>>>(BCD, A_log, dt_proj_b, Pc, Sc);
  scan_phase2<<<1, 512, 0, stream>>>(Pc, Sc, Init);
  scan_phase3<<<NCH * 4, 128, 0, stream>>>(BCD, A_log, dt_proj_b, Init, uvb, yg);
  // 6) out = x; out += yg @ out_proj (split-K=2, atomic epilogue)
  copyf4<<<(BT * DMODEL / 4) / 256, 256, 0, stream>>>((const float4*)x, (float4*)out);
  gemm_pipe<3><<<512, 256, 0, stream>>>(yg, opT, out, BT, DMODEL, 1024, EDIM, 32, DMODEL, 2);
  // 7) hb = rmsnorm(out)
  rmsnorm_bf16<<<BT, 256, 0, stream>>>(out, norm2_w, hb);
  // 8) ffb = swiglu(hb @ [w1|w3 ilv])  (8-phase, 512 blocks)
  gemm_big8<2><<<512, 512, 0, stream>>>(hb, w13T, ffb, BT, 8192, DMODEL, 16);
  // 9) out += ffb @ w2 (split-K=2, atomic epilogue)
  gemm_pipe<3><<<512, 256, 0, stream>>>(ffb, w2T, out, BT, DMODEL, 2048, DFF, 32, DMODEL, 2);
}